// Round 5
// baseline (37.286 us; speedup 1.0000x reference)
//
#include <hip/hip_runtime.h>

#define GDIM 104
#define GG (GDIM * GDIM)          // 10816
#define NA 3
#define NB 128
#define NBLK 1352                 // NB*GG / 1024
#define IMGF 832.0f
#define EPSF 1e-9f
#define PI_F 3.14159265358979323846f
#define INV_G (1.0f / 104.0f)

__device__ __forceinline__ float sigmoid_fast(float z) {
    return 1.0f / (1.0f + __expf(-z));
}

// acos minimax (Abramowitz-Stegun 4.4.45), |err| < 7e-5 rad
__device__ __forceinline__ float acos_fast(float x) {
    float ax = fabsf(x);
    float t = sqrtf(fmaxf(1.0f - ax, 0.0f));
    float p = fmaf(-0.0187293f, ax, 0.0742610f);
    p = fmaf(p, ax, -0.2121144f);
    p = fmaf(p, ax, 1.5707288f);
    float r = t * p;
    return (x < 0.0f) ? (PI_F - r) : r;
}

// 4 cells/thread, lane-contiguous: thread owns cells {base + c*256}.
// __launch_bounds__(256,4): allow up to ~128 VGPR so all 64 loads stay in
// flight (R4's 52-VGPR default serialized them -> 1.66 TB/s bytes-in-flight cap).
__global__ __launch_bounds__(256, 4) void det_main(const float* __restrict__ x,
                                                   const float* __restrict__ tg,
                                                   float4* __restrict__ out4,
                                                   float* __restrict__ ws) {
    const float PR[NA] = {20.0f / 8.0f, 50.0f / 8.0f, 110.0f / 8.0f};   // ANCHORS/stride
    const float AR[NA] = {20.0f / IMGF, 50.0f / IMGF, 110.0f / IMGF};   // ANCHORS/IMAGE_SIZE

    int base = blockIdx.x * 1024 + threadIdx.x;

    // ---- issue ALL 64 loads up front (lane-contiguous scalar loads) ----
    int bb[4], rr[4];
    float vt[4][4];     // targets [c][plane]
    float vp[4][12];    // x       [c][plane]
#pragma unroll
    for (int c = 0; c < 4; ++c) {
        int gc = base + c * 256;
        int b = gc / GG;
        int r = gc - b * GG;
        bb[c] = b; rr[c] = r;
        const float* tb = tg + (size_t)b * (4 * GG) + r;
#pragma unroll
        for (int p = 0; p < 4; ++p) vt[c][p] = tb[(size_t)p * GG];
        const float* xb = x + (size_t)b * (12 * GG) + r;
#pragma unroll
        for (int p = 0; p < 12; ++p) vp[c][p] = xb[(size_t)p * GG];
    }
    // keep every load issued before any compute is scheduled
    __builtin_amdgcn_sched_barrier(0);

    float l_fl = 0.0f, l_di = 0.0f;
    int   l_n  = 0;

#pragma unroll
    for (int c = 0; c < 4; ++c) {
        int b = bb[c], r = rr[c];
        int i = r / GDIM;
        int j = r - i * GDIM;
        float fi = (float)i, fj = (float)j;

        float tx  = vt[c][0];
        float ty  = vt[c][1];
        float trr = vt[c][2];
        float cf  = vt[c][3];
        float tgx = (fj + tx) * INV_G;
        float tgy = (fi + ty) * INV_G;

        // best anchor = argmax riou (first-max tie rule via strict >)
        int best = 0;
        float bestv = -1.0f;
#pragma unroll
        for (int a = 0; a < NA; ++a) {
            float q = fminf(trr, AR[a]) / (fmaxf(trr, AR[a]) + EPSF);
            float ri = q * q;
            if (ri > bestv) { bestv = ri; best = a; }
        }
        bool pos = (cf > 0.5f);

        size_t obase = (size_t)b * (NA * GG) + r;
        float sbx = 0.0f, sby = 0.0f, sbr = 0.0f;
#pragma unroll
        for (int a = 0; a < NA; ++a) {
            float p0 = vp[c][a * 4 + 0];
            float p1 = vp[c][a * 4 + 1];
            float p2 = vp[c][a * 4 + 2];
            float p3 = vp[c][a * 4 + 3];

            float sx = sigmoid_fast(p0);
            float sy = sigmoid_fast(p1);
            float br = PR[a] * __expf(p2) * INV_G;

            float e   = __expf(-p3);
            float pc  = 1.0f / (1.0f + e);
            float l1e = __logf(1.0f + e);     // = -log_sigmoid(p3)

            float4 o;
            o.x = (sx + fj) * 8.0f;
            o.y = (sy + fi) * 8.0f;
            o.z = br * IMGF;
            o.w = pc;
            out4[obase + (size_t)a * GG] = o;   // lane-contiguous 16B stores

            bool obj = pos && (a == best);
            float u = 1.0f - pc;
            l_fl += obj ? 0.25f * u * u * l1e : 0.75f * pc * pc * (p3 + l1e);

            if (a == best) { sbx = (sx + fj) * INV_G; sby = (sy + fi) * INV_G; sbr = br; }
        }

        if (pos) {
            l_n += 1;
            float dx = sbx - tgx, dy = sby - tgy;
            float d2 = dx * dx + dy * dy;
            float d  = sqrtf(d2 + EPSF);
            float r1 = sbr, r2 = trr;
            float rmin = fminf(r1, r2), rmax = fmaxf(r1, r2);
            float a1 = (d2 + r1 * r1 - r2 * r2) / (2.0f * d * r1 + EPSF);
            a1 = fminf(fmaxf(a1, -1.0f), 1.0f);
            float a2 = (d2 + r2 * r2 - r1 * r1) / (2.0f * d * r2 + EPSF);
            a2 = fminf(fmaxf(a2, -1.0f), 1.0f);
            float tt = (-d + r1 + r2) * (d + r1 - r2) * (d - r1 + r2) * (d + r1 + r2);
            tt = fmaxf(tt, 0.0f);
            float lens = r1 * r1 * acos_fast(a1) + r2 * r2 * acos_fast(a2) - 0.5f * sqrtf(tt);
            float inter = (d >= r1 + r2) ? 0.0f
                         : ((d <= rmax - rmin) ? PI_F * rmin * rmin : lens);
            float uni = PI_F * (r1 * r1 + r2 * r2) - inter;
            float iou = inter / (uni + EPSF);
            float s = d + r1 + r2;
            float pen = d2 / (s * s + EPSF);
            l_di += 1.0f - iou + pen;
        }
    }

    // wave64 reduce
    float l_nf = (float)l_n;
#pragma unroll
    for (int off = 32; off > 0; off >>= 1) {
        l_di += __shfl_down(l_di, off);
        l_fl += __shfl_down(l_fl, off);
        l_nf += __shfl_down(l_nf, off);
    }

    __shared__ float sdiou[4], sfl[4], sn[4];
    int wid  = threadIdx.x >> 6;
    int lane = threadIdx.x & 63;
    if (lane == 0) { sdiou[wid] = l_di; sfl[wid] = l_fl; sn[wid] = l_nf; }
    __syncthreads();
    if (threadIdx.x == 0) {
        float ds = 0.0f, fs = 0.0f, ns = 0.0f;
#pragma unroll
        for (int w = 0; w < 4; ++w) { ds += sdiou[w]; fs += sfl[w]; ns += sn[w]; }
        ws[blockIdx.x]            = ds;
        ws[NBLK + blockIdx.x]     = fs;
        ws[2 * NBLK + blockIdx.x] = ns;
    }
}

__global__ __launch_bounds__(256) void det_finalize(const float* __restrict__ ws,
                                                    float* __restrict__ out_scalar) {
    float ds = 0.0f, fs = 0.0f, ns = 0.0f;
    for (int k = threadIdx.x; k < NBLK; k += 256) {
        ds += ws[k];
        fs += ws[NBLK + k];
        ns += ws[2 * NBLK + k];
    }
#pragma unroll
    for (int off = 32; off > 0; off >>= 1) {
        ds += __shfl_down(ds, off);
        fs += __shfl_down(fs, off);
        ns += __shfl_down(ns, off);
    }
    __shared__ float s0[4], s1[4], s2[4];
    int wid  = threadIdx.x >> 6;
    int lane = threadIdx.x & 63;
    if (lane == 0) { s0[wid] = ds; s1[wid] = fs; s2[wid] = ns; }
    __syncthreads();
    if (threadIdx.x == 0) {
        float D = 0.0f, F = 0.0f, N = 0.0f;
#pragma unroll
        for (int w = 0; w < 4; ++w) { D += s0[w]; F += s1[w]; N += s2[w]; }
        double n = (N < 1.0f) ? 1.0 : (double)N;
        out_scalar[0] = (float)((double)D / n + (double)F / (double)((size_t)NB * NA * GG));
    }
}

extern "C" void kernel_launch(void* const* d_in, const int* in_sizes, int n_in,
                              void* d_out, int out_size, void* d_ws, size_t ws_size,
                              hipStream_t stream) {
    const float* x  = (const float*)d_in[0];
    const float* tg = (const float*)d_in[1];
    float* out = (float*)d_out;
    float* ws  = (float*)d_ws;

    det_main<<<NBLK, 256, 0, stream>>>(x, tg, (float4*)out, ws);
    det_finalize<<<1, 256, 0, stream>>>(ws, out + (size_t)NB * NA * GG * 4);
}

// Round 6
// 34.297 us; speedup vs baseline: 1.0872x; 1.0872x over previous
//
#include <hip/hip_runtime.h>

#define GDIM 104
#define GG (GDIM * GDIM)          // 10816
#define NA 3
#define NB 128
#define NBLK 1352                 // NB*GG / 1024
#define IMGF 832.0f
#define EPSF 1e-9f
#define PI_F 3.14159265358979323846f
#define INV_G (1.0f / 104.0f)

// 1-instruction reciprocal (v_rcp_f32, rel err ~2^-22 — fine at threshold 348)
__device__ __forceinline__ float rcp_(float x) { return __builtin_amdgcn_rcpf(x); }

__device__ __forceinline__ float sigmoid_fast(float z) {
    return rcp_(1.0f + __expf(-z));
}

// acos minimax (Abramowitz-Stegun 4.4.45), |err| < 7e-5 rad
__device__ __forceinline__ float acos_fast(float x) {
    float ax = fabsf(x);
    float t = sqrtf(fmaxf(1.0f - ax, 0.0f));
    float p = fmaf(-0.0187293f, ax, 0.0742610f);
    p = fmaf(p, ax, -0.2121144f);
    p = fmaf(p, ax, 1.5707288f);
    float r = t * p;
    return (x < 0.0f) ? (PI_F - r) : r;
}

// 4 cells/thread, lane-contiguous: thread owns cells {base + c*256}.
__global__ __launch_bounds__(256) void det_main(const float* __restrict__ x,
                                                const float* __restrict__ tg,
                                                float4* __restrict__ out4,
                                                float* __restrict__ ws) {
    const float PR[NA] = {20.0f / 8.0f, 50.0f / 8.0f, 110.0f / 8.0f};   // ANCHORS/stride
    const float AR[NA] = {20.0f / IMGF, 50.0f / IMGF, 110.0f / IMGF};   // ANCHORS/IMAGE_SIZE

    int base = blockIdx.x * 1024 + threadIdx.x;

    // ---- issue loads up front (lane-contiguous scalar loads) ----
    int bb[4], rr[4];
    float vt[4][4];     // targets [c][plane]
    float vp[4][12];    // x       [c][plane]
#pragma unroll
    for (int c = 0; c < 4; ++c) {
        int gc = base + c * 256;
        int b = gc / GG;
        int r = gc - b * GG;
        bb[c] = b; rr[c] = r;
        const float* tb = tg + (size_t)b * (4 * GG) + r;
#pragma unroll
        for (int p = 0; p < 4; ++p) vt[c][p] = tb[(size_t)p * GG];
        const float* xb = x + (size_t)b * (12 * GG) + r;
#pragma unroll
        for (int p = 0; p < 12; ++p) vp[c][p] = xb[(size_t)p * GG];
    }

    float l_fl = 0.0f, l_di = 0.0f;
    int   l_n  = 0;

#pragma unroll
    for (int c = 0; c < 4; ++c) {
        int b = bb[c], r = rr[c];
        int i = r / GDIM;
        int j = r - i * GDIM;
        float fi = (float)i, fj = (float)j;

        float tx  = vt[c][0];
        float ty  = vt[c][1];
        float trr = vt[c][2];
        float cf  = vt[c][3];
        float tgx = (fj + tx) * INV_G;
        float tgy = (fi + ty) * INV_G;

        // best anchor = argmax riou (first-max tie rule via strict >)
        int best = 0;
        float bestv = -1.0f;
#pragma unroll
        for (int a = 0; a < NA; ++a) {
            float q = fminf(trr, AR[a]) * rcp_(fmaxf(trr, AR[a]) + EPSF);
            float ri = q * q;
            if (ri > bestv) { bestv = ri; best = a; }
        }
        bool pos = (cf > 0.5f);

        size_t obase = (size_t)b * (NA * GG) + r;
        float sbx = 0.0f, sby = 0.0f, sbr = 0.0f;
#pragma unroll
        for (int a = 0; a < NA; ++a) {
            float p0 = vp[c][a * 4 + 0];
            float p1 = vp[c][a * 4 + 1];
            float p2 = vp[c][a * 4 + 2];
            float p3 = vp[c][a * 4 + 3];

            float sx = sigmoid_fast(p0);
            float sy = sigmoid_fast(p1);
            float br = PR[a] * __expf(p2) * INV_G;

            float e   = __expf(-p3);
            float pc  = rcp_(1.0f + e);
            float l1e = __logf(1.0f + e);     // = -log_sigmoid(p3)

            float4 o;
            o.x = (sx + fj) * 8.0f;
            o.y = (sy + fi) * 8.0f;
            o.z = br * IMGF;
            o.w = pc;
            out4[obase + (size_t)a * GG] = o;   // lane-contiguous 16B stores

            bool obj = pos && (a == best);
            float u = 1.0f - pc;
            l_fl += obj ? 0.25f * u * u * l1e : 0.75f * pc * pc * (p3 + l1e);

            if (a == best) { sbx = (sx + fj) * INV_G; sby = (sy + fi) * INV_G; sbr = br; }
        }

        if (pos) {
            l_n += 1;
            float dx = sbx - tgx, dy = sby - tgy;
            float d2 = dx * dx + dy * dy;
            float d  = sqrtf(d2 + EPSF);
            float r1 = sbr, r2 = trr;
            float rmin = fminf(r1, r2), rmax = fmaxf(r1, r2);
            float a1 = (d2 + r1 * r1 - r2 * r2) * rcp_(2.0f * d * r1 + EPSF);
            a1 = fminf(fmaxf(a1, -1.0f), 1.0f);
            float a2 = (d2 + r2 * r2 - r1 * r1) * rcp_(2.0f * d * r2 + EPSF);
            a2 = fminf(fmaxf(a2, -1.0f), 1.0f);
            float tt = (-d + r1 + r2) * (d + r1 - r2) * (d - r1 + r2) * (d + r1 + r2);
            tt = fmaxf(tt, 0.0f);
            float lens = r1 * r1 * acos_fast(a1) + r2 * r2 * acos_fast(a2) - 0.5f * sqrtf(tt);
            float inter = (d >= r1 + r2) ? 0.0f
                         : ((d <= rmax - rmin) ? PI_F * rmin * rmin : lens);
            float uni = PI_F * (r1 * r1 + r2 * r2) - inter;
            float iou = inter * rcp_(uni + EPSF);
            float s = d + r1 + r2;
            float pen = d2 * rcp_(s * s + EPSF);
            l_di += 1.0f - iou + pen;
        }
    }

    // wave64 reduce
    float l_nf = (float)l_n;
#pragma unroll
    for (int off = 32; off > 0; off >>= 1) {
        l_di += __shfl_down(l_di, off);
        l_fl += __shfl_down(l_fl, off);
        l_nf += __shfl_down(l_nf, off);
    }

    __shared__ float sdiou[4], sfl[4], sn[4];
    int wid  = threadIdx.x >> 6;
    int lane = threadIdx.x & 63;
    if (lane == 0) { sdiou[wid] = l_di; sfl[wid] = l_fl; sn[wid] = l_nf; }
    __syncthreads();
    if (threadIdx.x == 0) {
        float ds = 0.0f, fs = 0.0f, ns = 0.0f;
#pragma unroll
        for (int w = 0; w < 4; ++w) { ds += sdiou[w]; fs += sfl[w]; ns += sn[w]; }
        ws[blockIdx.x]            = ds;
        ws[NBLK + blockIdx.x]     = fs;
        ws[2 * NBLK + blockIdx.x] = ns;
    }
}

__global__ __launch_bounds__(256) void det_finalize(const float* __restrict__ ws,
                                                    float* __restrict__ out_scalar) {
    float ds = 0.0f, fs = 0.0f, ns = 0.0f;
    for (int k = threadIdx.x; k < NBLK; k += 256) {
        ds += ws[k];
        fs += ws[NBLK + k];
        ns += ws[2 * NBLK + k];
    }
#pragma unroll
    for (int off = 32; off > 0; off >>= 1) {
        ds += __shfl_down(ds, off);
        fs += __shfl_down(fs, off);
        ns += __shfl_down(ns, off);
    }
    __shared__ float s0[4], s1[4], s2[4];
    int wid  = threadIdx.x >> 6;
    int lane = threadIdx.x & 63;
    if (lane == 0) { s0[wid] = ds; s1[wid] = fs; s2[wid] = ns; }
    __syncthreads();
    if (threadIdx.x == 0) {
        float D = 0.0f, F = 0.0f, N = 0.0f;
#pragma unroll
        for (int w = 0; w < 4; ++w) { D += s0[w]; F += s1[w]; N += s2[w]; }
        double n = (N < 1.0f) ? 1.0 : (double)N;
        out_scalar[0] = (float)((double)D / n + (double)F / (double)((size_t)NB * NA * GG));
    }
}

extern "C" void kernel_launch(void* const* d_in, const int* in_sizes, int n_in,
                              void* d_out, int out_size, void* d_ws, size_t ws_size,
                              hipStream_t stream) {
    const float* x  = (const float*)d_in[0];
    const float* tg = (const float*)d_in[1];
    float* out = (float*)d_out;
    float* ws  = (float*)d_ws;

    det_main<<<NBLK, 256, 0, stream>>>(x, tg, (float4*)out, ws);
    det_finalize<<<1, 256, 0, stream>>>(ws, out + (size_t)NB * NA * GG * 4);
}